// Round 7
// baseline (6574.022 us; speedup 1.0000x reference)
//
#include <hip/hip_runtime.h>
#include <hip/hip_fp16.h>
#include <cstdint>
#include <cstddef>

// Problem constants (T, B, V, HID, L) from the reference.
#define TT 1024
#define BB 64
#define VV 256
#define HH 512
static const size_t TBH = (size_t)TT * BB * HH;   // 33,554,432 floats

typedef _Float16 half2v __attribute__((ext_vector_type(2)));
union U32H2 { unsigned u; half2v h; };

__device__ __forceinline__ unsigned pack_f16x2(float a, float b) {
    __half ha = __float2half_rn(a);
    __half hb = __float2half_rn(b);
    return (unsigned)__half_as_ushort(ha) | ((unsigned)__half_as_ushort(hb) << 16);
}

__device__ __forceinline__ float tanh_fast(float x) {
    // tanh(x) = sign(x) * (1 - e^-2|x|) / (1 + e^-2|x|)
    float ax = fabsf(x);
    float e = __expf(-2.0f * ax);
    float r = (1.0f - e) * __builtin_amdgcn_rcpf(1.0f + e);
    return copysignf(r, x);
}

__device__ __forceinline__ float fdot2(unsigned w, unsigned h, float acc) {
    U32H2 uw; uw.u = w;
    U32H2 uh; uh.u = h;
#if __has_builtin(__builtin_amdgcn_fdot2)
    return __builtin_amdgcn_fdot2(uw.h, uh.h, acc, false);
#else
    return acc + (float)uw.h[0] * (float)uh.h[0] + (float)uw.h[1] * (float)uh.h[1];
#endif
}

// h-LDS swizzle: pair j (dword) lives at dword index j ^ (((j>>5)&7)<<2).
// Involution; preserves uint4 groups (XOR is a multiple of 4 dwords). A
// wave's uint4 read at fixed q across kg=0..7 hits bank-quads (q^kg) -- all
// distinct -> conflict-free; the 8 lanes sharing kg broadcast (same addr).
__device__ __forceinline__ int swz_us(int r) {     // row -> ushort index
    int j = r >> 1;
    int js = j ^ (((j >> 5) & 7) << 2);
    return (js << 1) | (r & 1);
}

// All-VALU butterfly sum over lane bits 3..5 (the kg dimension): keeps the
// reduction OFF the LDS pipe.
__device__ __forceinline__ float bsum8(float v) {
    int d = __builtin_amdgcn_update_dpp(0, __float_as_int(v), 0x128, 0xF, 0xF, true);
    v += __int_as_float(d);
#if __has_builtin(__builtin_amdgcn_permlane16_swap) && __has_builtin(__builtin_amdgcn_permlane32_swap)
    {
        auto r1 = __builtin_amdgcn_permlane16_swap(__float_as_uint(v), __float_as_uint(v), false, false);
        v = __uint_as_float(r1[0]) + __uint_as_float(r1[1]);
        auto r2 = __builtin_amdgcn_permlane32_swap(__float_as_uint(v), __float_as_uint(v), false, false);
        v = __uint_as_float(r2[0]) + __uint_as_float(r2[1]);
    }
#else
    int l = (int)(threadIdx.x & 63);
    v += __int_as_float(__builtin_amdgcn_ds_bpermute((l ^ 16) << 2, __float_as_int(v)));
    v += __int_as_float(__builtin_amdgcn_ds_bpermute((l ^ 32) << 2, __float_as_int(v)));
#endif
    return v;
}

// ---------------------------------------------------------------------------
// Weight prep:
//  Wq0/Wq1 : recurrent Wh rows as f16x2 k-pairs   [512 rows][256 pairs]
//  Wp0/Wp1 : input-proj Wx^T as f16x2 k-pairs     [K/2 pairs][512 cols]
// ---------------------------------------------------------------------------
__global__ void pack_weights(const float* __restrict__ Wnet,
                             const float* __restrict__ Wdeep,
                             unsigned* __restrict__ Wq0, unsigned* __restrict__ Wq1,
                             unsigned* __restrict__ Wp0, unsigned* __restrict__ Wp1) {
    int id = blockIdx.x * 256 + threadIdx.x;
    const int NQ  = HH * (HH / 2);     // 131072
    const int NP0 = (VV / 2) * HH;     // 65536
    const int NP1 = (HH / 2) * HH;     // 131072
    if (id < NQ) {
        int i = id >> 8, jp = id & 255;
        const float* row = Wnet + (size_t)i * (VV + HH) + VV;   // Wh0[i][:]
        Wq0[id] = pack_f16x2(row[2 * jp], row[2 * jp + 1]);
        return;
    }
    id -= NQ;
    if (id < NQ) {
        int i = id >> 8, jp = id & 255;
        const float* row = Wdeep + (size_t)i * (2 * HH) + HH;   // Wh1[i][:]
        Wq1[id] = pack_f16x2(row[2 * jp], row[2 * jp + 1]);
        return;
    }
    id -= NQ;
    if (id < NP0) {
        int k2 = id >> 9, n = id & 511;                          // Wx0[n][2k2..]
        const float* row = Wnet + (size_t)n * (VV + HH);
        Wp0[id] = pack_f16x2(row[2 * k2], row[2 * k2 + 1]);
        return;
    }
    id -= NP0;
    if (id < NP1) {
        int k2 = id >> 9, n = id & 511;                          // Wx1[n][2k2..]
        const float* row = Wdeep + (size_t)n * (2 * HH);
        Wp1[id] = pack_f16x2(row[2 * k2], row[2 * k2 + 1]);
        return;
    }
}

// ---------------------------------------------------------------------------
// Input-projection GEMM (f16 dot2): C[M,512] = A[M,K] @ Wx^T + bias.
// ---------------------------------------------------------------------------
__device__ __forceinline__ void dot8(float* acc, unsigned a, uint4 w0, uint4 w1) {
    acc[0] = fdot2(w0.x, a, acc[0]);
    acc[1] = fdot2(w0.y, a, acc[1]);
    acc[2] = fdot2(w0.z, a, acc[2]);
    acc[3] = fdot2(w0.w, a, acc[3]);
    acc[4] = fdot2(w1.x, a, acc[4]);
    acc[5] = fdot2(w1.y, a, acc[5]);
    acc[6] = fdot2(w1.z, a, acc[6]);
    acc[7] = fdot2(w1.w, a, acc[7]);
}

__launch_bounds__(1024)
__global__ void xproj_f16(const float* __restrict__ A,
                          const unsigned* __restrict__ Wp,   // [K/2][512] f16x2
                          const float* __restrict__ bias,
                          float* __restrict__ C, int K) {
    extern __shared__ unsigned As2[];      // 32 rows * K/2 pairs
    const int m0 = blockIdx.x * 32;
    const int t = threadIdx.x;
    const int K2 = K >> 1;

    const int nf4 = 8 * K;                 // 32*K/4
    const float4* Ag = (const float4*)(A + (size_t)m0 * K);
    for (int idx = t; idx < nf4; idx += 1024) {
        float4 v = Ag[idx];
        As2[idx * 2]     = pack_f16x2(v.x, v.y);
        As2[idx * 2 + 1] = pack_f16x2(v.z, v.w);
    }
    __syncthreads();

    const int rg = t >> 6;                 // 2 rows per thread
    const int n0 = (t & 63) * 8;

    float acc0[8] = {0, 0, 0, 0, 0, 0, 0, 0};
    float acc1[8] = {0, 0, 0, 0, 0, 0, 0, 0};

    const unsigned* a0p = As2 + (size_t)(rg * 2) * K2;
    const unsigned* a1p = a0p + K2;

#pragma unroll 4
    for (int k2 = 0; k2 < K2; k2 += 2) {
        unsigned a00 = a0p[k2], a01 = a0p[k2 + 1];
        unsigned a10 = a1p[k2], a11 = a1p[k2 + 1];
        const uint4 w00 = *(const uint4*)(Wp + (size_t)k2 * 512 + n0);
        const uint4 w01 = *(const uint4*)(Wp + (size_t)k2 * 512 + n0 + 4);
        const uint4 w10 = *(const uint4*)(Wp + (size_t)(k2 + 1) * 512 + n0);
        const uint4 w11 = *(const uint4*)(Wp + (size_t)(k2 + 1) * 512 + n0 + 4);
        dot8(acc0, a00, w00, w01);
        dot8(acc1, a10, w00, w01);
        dot8(acc0, a01, w10, w11);
        dot8(acc1, a11, w10, w11);
    }

    float bv[8];
#pragma unroll
    for (int c = 0; c < 8; ++c) bv[c] = bias[n0 + c];

    float* Crow0 = C + (size_t)(m0 + rg * 2) * 512 + n0;
    float* Crow1 = Crow0 + 512;
    *(float4*)(Crow0)     = make_float4(acc0[0] + bv[0], acc0[1] + bv[1], acc0[2] + bv[2], acc0[3] + bv[3]);
    *(float4*)(Crow0 + 4) = make_float4(acc0[4] + bv[4], acc0[5] + bv[5], acc0[6] + bv[6], acc0[7] + bv[7]);
    *(float4*)(Crow1)     = make_float4(acc1[0] + bv[0], acc1[1] + bv[1], acc1[2] + bv[2], acc1[3] + bv[3]);
    *(float4*)(Crow1 + 4) = make_float4(acc1[4] + bv[4], acc1[5] + bv[5], acc1[6] + bv[6], acc1[7] + bv[7]);
}

// ---------------------------------------------------------------------------
// RNN scan v8: one WG per batch, weights rows j=6,7 streamed from GLOBAL (L2)
// instead of LDS.
// v5-v7 post-mortem: step invariant at ~3900 cyc across all scheduling fixes;
// LDS pipe recount shows 192 ds_read_b128/CU/step (~2300 cyc) -- the weight
// re-stream (128 KB/step) was 2/3 of the critical pipe.  With only 64/256
// CUs active, per-XCD L2 (~4.3 TB/s) gives each active CU ~225 B/cyc --
// MORE than the 128 B/cyc LDS pipe -- and all 8 WGs/XCD share the same
// 512 KB L2-resident weight matrix.  Moving w6/w7 to buffer loads:
//  * LDS pipe drops to ~850 cyc/step (hq broadcast reads + h write)
//  * weight loads count in vmcnt -> sail through the lgkmcnt-only barrier
//  * Wl LDS region disappears -> static 2 KB LDS, no big-LDS opt-in path
// Same q-level 1-deep software pipeline hides the ~200 cyc L2-hit latency
// under 32 dots/stage (+ 8-wave TLP).
// ---------------------------------------------------------------------------
__launch_bounds__(512, 1)
__global__ void rnn_scan8(const unsigned* __restrict__ Wq,   // [512][256] f16x2
                          const float* __restrict__ h0,      // [B][512]
                          float* __restrict__ states,        // [T][B][512] in:pre out:h
                          float* __restrict__ last) {        // [B][512]
    __shared__ unsigned short hsh0[HH];
    __shared__ unsigned short hsh1[HH];

    const int b = blockIdx.x;
    const int tid = threadIdx.x;
    const int w = tid >> 6;
    const int lane = tid & 63;
    const int rowsub = lane & 7;
    const int kg = lane >> 3;
    const int rfin = w * 64 + rowsub + 8 * kg;   // the row this thread finalizes

    // --- resident weights: rows j=0..5, my kg chunk (48 uint4 = 192 regs) ---
    uint4 wreg[6][8];
#pragma unroll
    for (int j = 0; j < 6; ++j) {
        const uint4* Wr = (const uint4*)(Wq + (size_t)(w * 64 + rowsub + 8 * j) * 256) + kg * 8;
#pragma unroll
        for (int q = 0; q < 8; ++q) wreg[j][q] = Wr[q];
    }
    // --- streamed weights: rows j=6,7 read from global every step (L2-hot:
    //     512 KB shared by all 8 WGs on the XCD) ---
    const uint4* g6 = (const uint4*)(Wq + (size_t)(w * 64 + rowsub + 48) * 256) + kg * 8;
    const uint4* g7 = (const uint4*)(Wq + (size_t)(w * 64 + rowsub + 56) * 256) + kg * 8;

    // --- stage h0 as f16 into hsh1 (buffer read at even t) ---
    hsh1[swz_us(tid)] = __half_as_ushort(__float2half_rn(h0[(size_t)b * HH + tid]));
    __syncthreads();   // once; full drain here is fine

    const int hoff = kg * 8;                   // uint4 base of my h chunk
    const int wswz = swz_us(rfin);             // my h write slot (ushort idx)

    size_t base = (size_t)b * HH;
    const size_t tstride = (size_t)BB * HH;
    float pre_cur = states[base + rfin];
    float h = 0.f;

    const uint4* hbA = (const uint4*)hsh1;     // read at even t (h0 / odd-t writes)
    const uint4* hbB = (const uint4*)hsh0;     // read at odd t  (even-t writes)

    auto step = [&](const uint4* __restrict__ hbr, unsigned short* __restrict__ hshw, int t) {
        float pre_nxt = 0.f;
        if (t + 1 < TT) pre_nxt = states[base + tstride + rfin];   // in flight across barrier

        // software pipeline: current {hq,w6,w7} in regs, next issued during dots
        uint4 hq = hbr[hoff + (0 ^ kg)];
        uint4 w6 = g6[0];
        uint4 w7 = g7[0];

        float a0 = 0.f, a1 = 0.f, a2 = 0.f, a3 = 0.f;
        float a4 = 0.f, a5 = 0.f, a6 = 0.f, a7 = 0.f;
#pragma unroll
        for (int q = 0; q < 8; ++q) {
            uint4 hq_n, w6_n, w7_n;
            if (q < 7) {                       // issue q+1's loads before q's dots
                hq_n = hbr[hoff + ((q + 1) ^ kg)];
                w6_n = g6[q + 1];
                w7_n = g7[q + 1];
            }
            a0 = fdot2(wreg[0][q].x, hq.x, a0);
            a0 = fdot2(wreg[0][q].y, hq.y, a0);
            a0 = fdot2(wreg[0][q].z, hq.z, a0);
            a0 = fdot2(wreg[0][q].w, hq.w, a0);
            a1 = fdot2(wreg[1][q].x, hq.x, a1);
            a1 = fdot2(wreg[1][q].y, hq.y, a1);
            a1 = fdot2(wreg[1][q].z, hq.z, a1);
            a1 = fdot2(wreg[1][q].w, hq.w, a1);
            a2 = fdot2(wreg[2][q].x, hq.x, a2);
            a2 = fdot2(wreg[2][q].y, hq.y, a2);
            a2 = fdot2(wreg[2][q].z, hq.z, a2);
            a2 = fdot2(wreg[2][q].w, hq.w, a2);
            a3 = fdot2(wreg[3][q].x, hq.x, a3);
            a3 = fdot2(wreg[3][q].y, hq.y, a3);
            a3 = fdot2(wreg[3][q].z, hq.z, a3);
            a3 = fdot2(wreg[3][q].w, hq.w, a3);
            a4 = fdot2(wreg[4][q].x, hq.x, a4);
            a4 = fdot2(wreg[4][q].y, hq.y, a4);
            a4 = fdot2(wreg[4][q].z, hq.z, a4);
            a4 = fdot2(wreg[4][q].w, hq.w, a4);
            a5 = fdot2(wreg[5][q].x, hq.x, a5);
            a5 = fdot2(wreg[5][q].y, hq.y, a5);
            a5 = fdot2(wreg[5][q].z, hq.z, a5);
            a5 = fdot2(wreg[5][q].w, hq.w, a5);
            a6 = fdot2(w6.x, hq.x, a6);
            a6 = fdot2(w6.y, hq.y, a6);
            a6 = fdot2(w6.z, hq.z, a6);
            a6 = fdot2(w6.w, hq.w, a6);
            a7 = fdot2(w7.x, hq.x, a7);
            a7 = fdot2(w7.y, hq.y, a7);
            a7 = fdot2(w7.z, hq.z, a7);
            a7 = fdot2(w7.w, hq.w, a7);
            if (q < 7) { hq = hq_n; w6 = w6_n; w7 = w7_n; }
        }
        // all-VALU kg-reduction (LDS pipe stays free)
        a0 = bsum8(a0); a1 = bsum8(a1); a2 = bsum8(a2); a3 = bsum8(a3);
        a4 = bsum8(a4); a5 = bsum8(a5); a6 = bsum8(a6); a7 = bsum8(a7);

        // this thread finalizes row rfin (chain j == kg): static select
        float af = (kg == 0) ? a0 : (kg == 1) ? a1 : (kg == 2) ? a2 : (kg == 3) ? a3
                 : (kg == 4) ? a4 : (kg == 5) ? a5 : (kg == 6) ? a6 : a7;
        h = tanh_fast(pre_cur + af);
        states[base + rfin] = h;               // fire-and-forget (never drained in-loop)
        hshw[wswz] = __half_as_ushort(__float2half_rn(h));

        // Counted-wait barrier (T4): only LDS must be visible across waves.
        // vmcnt (weight/pre loads, h store) is never drained in-loop.
        asm volatile("s_waitcnt lgkmcnt(0)" ::: "memory");
        __builtin_amdgcn_s_barrier();
        __builtin_amdgcn_sched_barrier(0);     // rule #18: pin reads after barrier

        pre_cur = pre_nxt;
        base += tstride;
    };

    for (int t = 0; t < TT; t += 2) {
        step(hbA, hsh0, t);        // even t: read h(t-1) from hsh1, write h(t) -> hsh0
        step(hbB, hsh1, t + 1);    // odd  t: read from hsh0, write -> hsh1
    }

    last[(size_t)b * HH + rfin] = h;
}

// ---------------------------------------------------------------------------
extern "C" void kernel_launch(void* const* d_in, const int* in_sizes, int n_in,
                              void* d_out, int out_size, void* d_ws, size_t ws_size,
                              hipStream_t stream) {
    (void)in_sizes; (void)n_in; (void)out_size; (void)ws_size;
    const float* inputs = (const float*)d_in[0];   // (T,B,V)
    const float* H      = (const float*)d_in[1];   // (L,B,HID)
    const float* Wnet   = (const float*)d_in[2];   // (HID, V+HID)
    const float* bnet   = (const float*)d_in[3];   // (HID,)
    const float* Wdeep  = (const float*)d_in[4];   // (HID, 2*HID)
    const float* bdeep  = (const float*)d_in[5];   // (HID,)
    float* out = (float*)d_out;

    // workspace layout: packed weights only (~1.75 MB)
    unsigned* Wq0 = (unsigned*)d_ws;                    // 131072 u32
    unsigned* Wq1 = Wq0 + HH * (HH / 2);                // 131072 u32
    unsigned* Wp0 = Wq1 + HH * (HH / 2);                // 65536 u32
    unsigned* Wp1 = Wp0 + (VV / 2) * HH;                // 131072 u32

    // 1) pack weights (458752 ids / 256 = 1792 blocks)
    hipLaunchKernelGGL(pack_weights, dim3(1792), dim3(256), 0, stream,
                       Wnet, Wdeep, Wq0, Wq1, Wp0, Wp1);

    // 2) pre0 = inputs @ Wx0^T + b_net  -> d_out[0:TBH]
    hipLaunchKernelGGL(xproj_f16, dim3((TT * BB) / 32), dim3(1024),
                       32 * (VV / 2) * sizeof(unsigned), stream,
                       inputs, Wp0, bnet, out, VV);

    // 3) layer-0 scan (one WG per batch element)
    hipLaunchKernelGGL(rnn_scan8, dim3(64), dim3(512), 0, stream,
                       Wq0, H, out, out + TBH);

    // 4) pre1 = states0 @ Wx1^T + b_deep (in-place over d_out)
    hipLaunchKernelGGL(xproj_f16, dim3((TT * BB) / 32), dim3(1024),
                       32 * (HH / 2) * sizeof(unsigned), stream,
                       out, Wp1, bdeep, out, HH);

    // 5) layer-1 scan
    hipLaunchKernelGGL(rnn_scan8, dim3(64), dim3(512), 0, stream,
                       Wq1, H + (size_t)BB * HH, out, out + TBH + (size_t)BB * HH);
}

// Round 8
// 4183.721 us; speedup vs baseline: 1.5713x; 1.5713x over previous
//
#include <hip/hip_runtime.h>
#include <hip/hip_fp16.h>
#include <cstdint>
#include <cstddef>

// Problem constants (T, B, V, HID, L) from the reference.
#define TT 1024
#define BB 64
#define VV 256
#define HH 512
static const size_t TBH = (size_t)TT * BB * HH;   // 33,554,432 floats

#define AGENT __HIP_MEMORY_SCOPE_AGENT

typedef _Float16 half2v __attribute__((ext_vector_type(2)));
union U32H2 { unsigned u; half2v h; };

__device__ __forceinline__ unsigned pack_f16x2(float a, float b) {
    __half ha = __float2half_rn(a);
    __half hb = __float2half_rn(b);
    return (unsigned)__half_as_ushort(ha) | ((unsigned)__half_as_ushort(hb) << 16);
}

__device__ __forceinline__ float tanh_fast(float x) {
    // tanh(x) = sign(x) * (1 - e^-2|x|) / (1 + e^-2|x|)
    float ax = fabsf(x);
    float e = __expf(-2.0f * ax);
    float r = (1.0f - e) * __builtin_amdgcn_rcpf(1.0f + e);
    return copysignf(r, x);
}

__device__ __forceinline__ float fdot2(unsigned w, unsigned h, float acc) {
    U32H2 uw; uw.u = w;
    U32H2 uh; uh.u = h;
#if __has_builtin(__builtin_amdgcn_fdot2)
    return __builtin_amdgcn_fdot2(uw.h, uh.h, acc, false);
#else
    return acc + (float)uw.h[0] * (float)uh.h[0] + (float)uw.h[1] * (float)uh.h[1];
#endif
}

// h-LDS swizzle: pair j (dword) lives at dword index j ^ (((j>>5)&7)<<2).
// Involution; preserves uint4 groups. A wave's uint4 read at fixed q across
// kg=0..7 hits bank-quads 4*(q^kg) -- all distinct -> conflict-free; the 8
// lanes sharing kg broadcast (same addr).
__device__ __forceinline__ int swz_us(int r) {     // row -> ushort index
    int j = r >> 1;
    int js = j ^ (((j >> 5) & 7) << 2);
    return (js << 1) | (r & 1);
}

// All-VALU butterfly sum over lane bits 3..5 (the kg dimension).
__device__ __forceinline__ float bsum8(float v) {
    int d = __builtin_amdgcn_update_dpp(0, __float_as_int(v), 0x128, 0xF, 0xF, true);
    v += __int_as_float(d);
#if __has_builtin(__builtin_amdgcn_permlane16_swap) && __has_builtin(__builtin_amdgcn_permlane32_swap)
    {
        auto r1 = __builtin_amdgcn_permlane16_swap(__float_as_uint(v), __float_as_uint(v), false, false);
        v = __uint_as_float(r1[0]) + __uint_as_float(r1[1]);
        auto r2 = __builtin_amdgcn_permlane32_swap(__float_as_uint(v), __float_as_uint(v), false, false);
        v = __uint_as_float(r2[0]) + __uint_as_float(r2[1]);
    }
#else
    int l = (int)(threadIdx.x & 63);
    v += __int_as_float(__builtin_amdgcn_ds_bpermute((l ^ 16) << 2, __float_as_int(v)));
    v += __int_as_float(__builtin_amdgcn_ds_bpermute((l ^ 32) << 2, __float_as_int(v)));
#endif
    return v;
}

// ---------------------------------------------------------------------------
// Weight prep:
//  Wq0/Wq1 : recurrent Wh rows as f16x2 k-pairs   [512 rows][256 pairs]
//  Wp0/Wp1 : input-proj Wx^T as f16x2 k-pairs     [K/2 pairs][512 cols]
// ---------------------------------------------------------------------------
__global__ void pack_weights(const float* __restrict__ Wnet,
                             const float* __restrict__ Wdeep,
                             unsigned* __restrict__ Wq0, unsigned* __restrict__ Wq1,
                             unsigned* __restrict__ Wp0, unsigned* __restrict__ Wp1) {
    int id = blockIdx.x * 256 + threadIdx.x;
    const int NQ  = HH * (HH / 2);     // 131072
    const int NP0 = (VV / 2) * HH;     // 65536
    const int NP1 = (HH / 2) * HH;     // 131072
    if (id < NQ) {
        int i = id >> 8, jp = id & 255;
        const float* row = Wnet + (size_t)i * (VV + HH) + VV;   // Wh0[i][:]
        Wq0[id] = pack_f16x2(row[2 * jp], row[2 * jp + 1]);
        return;
    }
    id -= NQ;
    if (id < NQ) {
        int i = id >> 8, jp = id & 255;
        const float* row = Wdeep + (size_t)i * (2 * HH) + HH;   // Wh1[i][:]
        Wq1[id] = pack_f16x2(row[2 * jp], row[2 * jp + 1]);
        return;
    }
    id -= NQ;
    if (id < NP0) {
        int k2 = id >> 9, n = id & 511;                          // Wx0[n][2k2..]
        const float* row = Wnet + (size_t)n * (VV + HH);
        Wp0[id] = pack_f16x2(row[2 * k2], row[2 * k2 + 1]);
        return;
    }
    id -= NP0;
    if (id < NP1) {
        int k2 = id >> 9, n = id & 511;                          // Wx1[n][2k2..]
        const float* row = Wdeep + (size_t)n * (2 * HH);
        Wp1[id] = pack_f16x2(row[2 * k2], row[2 * k2 + 1]);
        return;
    }
}

// ---------------------------------------------------------------------------
// Input-projection GEMM (f16 dot2): C[M,512] = A[M,K] @ Wx^T + bias.
// ---------------------------------------------------------------------------
__device__ __forceinline__ void dot8(float* acc, unsigned a, uint4 w0, uint4 w1) {
    acc[0] = fdot2(w0.x, a, acc[0]);
    acc[1] = fdot2(w0.y, a, acc[1]);
    acc[2] = fdot2(w0.z, a, acc[2]);
    acc[3] = fdot2(w0.w, a, acc[3]);
    acc[4] = fdot2(w1.x, a, acc[4]);
    acc[5] = fdot2(w1.y, a, acc[5]);
    acc[6] = fdot2(w1.z, a, acc[6]);
    acc[7] = fdot2(w1.w, a, acc[7]);
}

__launch_bounds__(1024)
__global__ void xproj_f16(const float* __restrict__ A,
                          const unsigned* __restrict__ Wp,   // [K/2][512] f16x2
                          const float* __restrict__ bias,
                          float* __restrict__ C, int K) {
    extern __shared__ unsigned As2[];      // 32 rows * K/2 pairs
    const int m0 = blockIdx.x * 32;
    const int t = threadIdx.x;
    const int K2 = K >> 1;

    const int nf4 = 8 * K;                 // 32*K/4
    const float4* Ag = (const float4*)(A + (size_t)m0 * K);
    for (int idx = t; idx < nf4; idx += 1024) {
        float4 v = Ag[idx];
        As2[idx * 2]     = pack_f16x2(v.x, v.y);
        As2[idx * 2 + 1] = pack_f16x2(v.z, v.w);
    }
    __syncthreads();

    const int rg = t >> 6;                 // 2 rows per thread
    const int n0 = (t & 63) * 8;

    float acc0[8] = {0, 0, 0, 0, 0, 0, 0, 0};
    float acc1[8] = {0, 0, 0, 0, 0, 0, 0, 0};

    const unsigned* a0p = As2 + (size_t)(rg * 2) * K2;
    const unsigned* a1p = a0p + K2;

#pragma unroll 4
    for (int k2 = 0; k2 < K2; k2 += 2) {
        unsigned a00 = a0p[k2], a01 = a0p[k2 + 1];
        unsigned a10 = a1p[k2], a11 = a1p[k2 + 1];
        const uint4 w00 = *(const uint4*)(Wp + (size_t)k2 * 512 + n0);
        const uint4 w01 = *(const uint4*)(Wp + (size_t)k2 * 512 + n0 + 4);
        const uint4 w10 = *(const uint4*)(Wp + (size_t)(k2 + 1) * 512 + n0);
        const uint4 w11 = *(const uint4*)(Wp + (size_t)(k2 + 1) * 512 + n0 + 4);
        dot8(acc0, a00, w00, w01);
        dot8(acc1, a10, w00, w01);
        dot8(acc0, a01, w10, w11);
        dot8(acc1, a11, w10, w11);
    }

    float bv[8];
#pragma unroll
    for (int c = 0; c < 8; ++c) bv[c] = bias[n0 + c];

    float* Crow0 = C + (size_t)(m0 + rg * 2) * 512 + n0;
    float* Crow1 = Crow0 + 512;
    *(float4*)(Crow0)     = make_float4(acc0[0] + bv[0], acc0[1] + bv[1], acc0[2] + bv[2], acc0[3] + bv[3]);
    *(float4*)(Crow0 + 4) = make_float4(acc0[4] + bv[4], acc0[5] + bv[5], acc0[6] + bv[6], acc0[7] + bv[7]);
    *(float4*)(Crow1)     = make_float4(acc1[0] + bv[0], acc1[1] + bv[1], acc1[2] + bv[2], acc1[3] + bv[3]);
    *(float4*)(Crow1 + 4) = make_float4(acc1[4] + bv[4], acc1[5] + bv[5], acc1[6] + bv[6], acc1[7] + bv[7]);
}

// ---------------------------------------------------------------------------
// RNN scan v9: 4 WGs per batch element -> ALL 256 CUs active.
// Post-mortems: every 1-2-CU/batch variant floored at ~3850 cyc/step, and
// the counters resolve it as VALU-issue-bound (~2850 cyc: dots + AGPR moves
// + addressing) + ~1000-1500 cyc serial chain; v8 showed the global-load
// path is WORSE than LDS.  Fix is parallelism + footprint:
//  * WG s of 4 owns 128 rows; thread = 2 rows x 32 k-pairs -> 64 fdot2/step
//    (1/4 of v5) and 64 weight dwords -> fits ARCH VGPRs, zero AGPR moves.
//  * h via 8 broadcast ds_read_b128 (kg-XOR swizzle, loop-invariant addrs);
//    kg-reduction all-VALU (bsum8); LDS/CU/step ~64 b128.
//  * Exchange: v3/v4-proven tagged-u64 relaxed agent mailbox, parity
//    double-buffered; each WG publishes its 128 finalized h, 384 pollers
//    import the 3 foreign quarters.  WGs {b,b+64,b+128,b+192} -> same XCD
//    (b mod 8) so mailbox stays in one L2.
//  * Counted lgkmcnt-only barrier (T4): global stores/loads fly across.
// ---------------------------------------------------------------------------
__launch_bounds__(512, 1)
__global__ void rnn_scan9(const unsigned* __restrict__ Wq,   // [512][256] f16x2
                          const float* __restrict__ h0,      // [B][512]
                          float* __restrict__ states,        // [T][B][512] in:pre out:h
                          float* __restrict__ last,          // [B][512]
                          unsigned long long* __restrict__ X) { // [B][4 qtr][2 par][128]
    __shared__ unsigned short hshA[HH];    // read at even t (h0 / odd-t writes)
    __shared__ unsigned short hshB[HH];    // read at odd t  (even-t writes)

    const int wg = blockIdx.x;
    const int b = wg & 63;
    const int s = wg >> 6;                 // quarter 0..3: rows [s*128, +128)
    const int tid = threadIdx.x;
    const int w = tid >> 6;                // wave: rows [s*128+w*16, +16)
    const int lane = tid & 63;
    const int rowsub = lane & 7;
    const int kg = lane >> 3;              // k-chunk: pairs [kg*32, +32)

    const int r0 = s * 128 + w * 16 + rowsub;   // row j=0 (j=1 is r0+8)

    // finalizers: kg<2 -> row rf = s*128 + w*16 + (lane&15); kg==0 takes the
    // j=0 sum, kg==1 the j=1 sum (r1 = r0+8 with rowsub=lane-8 == rf).
    const bool is_fin = (kg < 2);
    const int rf = s * 128 + w * 16 + (lane & 15);
    const int fslot = w * 16 + (lane & 15);     // 0..127 within quarter

    // pollers: tid<384 import foreign quarter rows
    const bool is_poll = (tid < 384);
    const int qq = (s + 1 + (tid >> 7)) & 3;    // foreign quarter
    const int fr = tid & 127;                   // its row 0..127
    const int hrow = qq * 128 + fr;             // global row imported

    // --- weights: 2 rows x 8 uint4 = 64 dwords, ALL in arch VGPRs ---
    uint4 wreg[2][8];
#pragma unroll
    for (int j = 0; j < 2; ++j) {
        const uint4* Wr = (const uint4*)(Wq + (size_t)(r0 + 8 * j) * 256) + kg * 8;
#pragma unroll
        for (int q = 0; q < 8; ++q) wreg[j][q] = Wr[q];
    }

    // mailbox slots (parity-selected per step)
    unsigned long long* wrA   = X + ((((size_t)b * 4 + s)  * 2 + 0) << 7) + fslot;
    unsigned long long* wrB   = wrA + 128;
    unsigned long long* pollA = X + ((((size_t)b * 4 + qq) * 2 + 0) << 7) + fr;
    unsigned long long* pollB = pollA + 128;

    // --- stage h0 as f16 into hshA (buffer read at t=0) ---
    hshA[swz_us(tid)] = __half_as_ushort(__float2half_rn(h0[(size_t)b * HH + tid]));
    __syncthreads();   // once; full drain fine

    size_t base = (size_t)b * HH;
    const size_t tstride = (size_t)BB * HH;
    float pre_cur = 0.f;
    if (is_fin) pre_cur = states[base + rf];
    float h = 0.f;

    auto step = [&](const unsigned short* __restrict__ hbr,
                    unsigned short* __restrict__ hshw, int t) {
        float pre_nxt = 0.f;
        if (is_fin && t + 1 < TT) pre_nxt = states[base + tstride + rf];  // flies across barrier

        // 64 dots: 2 rows x 32 pairs; 2 chains/row for ILP
        const uint4* hb = (const uint4*)hbr;
        float a0 = 0.f, a1 = 0.f, c0 = 0.f, c1 = 0.f;
#pragma unroll
        for (int q = 0; q < 8; ++q) {
            const uint4 hq = hb[kg * 8 + (q ^ kg)];   // broadcast within kg-group
            a0 = fdot2(wreg[0][q].x, hq.x, a0);
            a1 = fdot2(wreg[0][q].y, hq.y, a1);
            a0 = fdot2(wreg[0][q].z, hq.z, a0);
            a1 = fdot2(wreg[0][q].w, hq.w, a1);
            c0 = fdot2(wreg[1][q].x, hq.x, c0);
            c1 = fdot2(wreg[1][q].y, hq.y, c1);
            c0 = fdot2(wreg[1][q].z, hq.z, c0);
            c1 = fdot2(wreg[1][q].w, hq.w, c1);
        }
        float ra = bsum8(a0 + a1);     // row j=0 sum, all lanes
        float rc = bsum8(c0 + c1);     // row j=1 sum, all lanes

        const int p = t & 1;
        if (is_fin) {
            float af = (kg == 0) ? ra : rc;
            h = tanh_fast(pre_cur + af);
            states[base + rf] = h;                    // fire-and-forget
            unsigned long long msg = ((unsigned long long)(unsigned)(t + 1) << 32)
                                   | (unsigned long long)__float_as_uint(h);
            __hip_atomic_store(p ? wrB : wrA, msg, __ATOMIC_RELAXED, AGENT);
            hshw[swz_us(rf)] = __half_as_ushort(__float2half_rn(h));
        }
        if (is_poll) {
            unsigned long long* slot = p ? pollB : pollA;
            unsigned long long v;
            do {
                v = __hip_atomic_load(slot, __ATOMIC_RELAXED, AGENT);
            } while ((unsigned)(v >> 32) != (unsigned)(t + 1));
            hshw[swz_us(hrow)] =
                __half_as_ushort(__float2half_rn(__uint_as_float((unsigned)v)));
        }

        // Counted-wait barrier (T4): only LDS must be visible across waves;
        // vmcnt (states store/load, mailbox) is never drained in-loop.
        asm volatile("s_waitcnt lgkmcnt(0)" ::: "memory");
        __builtin_amdgcn_s_barrier();
        __builtin_amdgcn_sched_barrier(0);            // rule #18

        pre_cur = pre_nxt;
        base += tstride;
    };

    for (int t = 0; t < TT; t += 2) {
        step(hshA, hshB, t);       // even t: read h(t-1) from hshA, write h(t) -> hshB
        step(hshB, hshA, t + 1);   // odd  t: read hshB, write hshA
    }

    if (is_fin) last[(size_t)b * HH + rf] = h;
}

// ---------------------------------------------------------------------------
extern "C" void kernel_launch(void* const* d_in, const int* in_sizes, int n_in,
                              void* d_out, int out_size, void* d_ws, size_t ws_size,
                              hipStream_t stream) {
    (void)in_sizes; (void)n_in; (void)out_size; (void)ws_size;
    const float* inputs = (const float*)d_in[0];   // (T,B,V)
    const float* H      = (const float*)d_in[1];   // (L,B,HID)
    const float* Wnet   = (const float*)d_in[2];   // (HID, V+HID)
    const float* bnet   = (const float*)d_in[3];   // (HID,)
    const float* Wdeep  = (const float*)d_in[4];   // (HID, 2*HID)
    const float* bdeep  = (const float*)d_in[5];   // (HID,)
    float* out = (float*)d_out;

    // workspace layout (X first for 8B alignment); ~2.3 MB total
    unsigned long long* X = (unsigned long long*)d_ws;  // 64*4*2*128 u64 = 512 KB
    unsigned* Wq0 = (unsigned*)(X + 64 * 4 * 2 * 128);  // 131072 u32
    unsigned* Wq1 = Wq0 + HH * (HH / 2);                // 131072 u32
    unsigned* Wp0 = Wq1 + HH * (HH / 2);                // 65536 u32
    unsigned* Wp1 = Wp0 + (VV / 2) * HH;                // 131072 u32

    // 1) pack weights (458752 ids / 256 = 1792 blocks)
    hipLaunchKernelGGL(pack_weights, dim3(1792), dim3(256), 0, stream,
                       Wnet, Wdeep, Wq0, Wq1, Wp0, Wp1);

    // 2) pre0 = inputs @ Wx0^T + b_net  -> d_out[0:TBH]
    hipLaunchKernelGGL(xproj_f16, dim3((TT * BB) / 32), dim3(1024),
                       32 * (VV / 2) * sizeof(unsigned), stream,
                       inputs, Wp0, bnet, out, VV);

    // 3) layer-0 scan (4 WGs per batch element, 256 CUs)
    hipLaunchKernelGGL(rnn_scan9, dim3(256), dim3(512), 0, stream,
                       Wq0, H, out, out + TBH, X);

    // 4) pre1 = states0 @ Wx1^T + b_deep (in-place over d_out)
    hipLaunchKernelGGL(xproj_f16, dim3((TT * BB) / 32), dim3(1024),
                       32 * (HH / 2) * sizeof(unsigned), stream,
                       out, Wp1, bdeep, out, HH);

    // 5) layer-1 scan (X reusable: exact-tag matching ignores stale tags)
    hipLaunchKernelGGL(rnn_scan9, dim3(256), dim3(512), 0, stream,
                       Wq1, H + (size_t)BB * HH, out, out + TBH + (size_t)BB * HH, X);
}